// Round 1
// baseline (292.880 us; speedup 1.0000x reference)
//
#include <hip/hip_runtime.h>

// ConvTranspose2d, stride=2, pad=1, k=4, groups=24 (one channel each).
// x: [8,1,24,256,256] f32; w: [24,1,1,4,4] f32; b: [24] f32
// y: [8,1,24,512,512] f32
//
// y[oh,ow] = sum_{t,u in {0,1}} w[rIdx(ph,t)][cIdx(pw,u)] * x[rowA+t][colA+u] + b
//   ph=oh&1, pw=ow&1
//   rowA = (oh>>1) + ph - 1 ; colA = (ow>>1) + pw - 1
//   rIdx(0,·)=(3,1), rIdx(1,·)=(2,0); cIdx identical.

#define NS 24
#define IH 256
#define IW 256
#define OHH 512
#define OWW 512

__global__ __launch_bounds__(256) void convt2x_kernel(
    const float* __restrict__ x, const float* __restrict__ w,
    const float* __restrict__ bias, float* __restrict__ out)
{
    const int b = blockIdx.z;
    const int s = blockIdx.y;
    const int lin = blockIdx.x * 256 + threadIdx.x;   // 0 .. 512*128-1
    const int oh = lin >> 7;        // output row 0..511
    const int qw = lin & 127;       // quad index along width
    const int c  = qw * 2;          // base input column
    const int r  = oh >> 1;
    const int ph = oh & 1;
    const int rowA = r + ph - 1;
    const int rowB = rowA + 1;

    const float* ximg = x + (size_t)(b * NS + s) * IH * IW;
    const float* wv   = w + s * 16;

    // Effective row-weight vectors for the two input-row taps.
    const int rA = ph ? 2 : 3;
    const int rB = ph ? 0 : 1;
    float w0r[4], w1r[4];
    #pragma unroll
    for (int k = 0; k < 4; ++k) {
        w0r[k] = wv[rA * 4 + k];
        w1r[k] = wv[rB * 4 + k];
    }
    const float bb = bias[s];

    const bool vA = (rowA >= 0);
    const bool vB = (rowB < IH);
    const float* pA = ximg + (size_t)rowA * IW;
    const float* pB = ximg + (size_t)rowB * IW;

    float xA[4], xB[4];
    #pragma unroll
    for (int k = 0; k < 4; ++k) {
        const int col = c - 1 + k;
        const bool vc = (col >= 0) && (col < IW);
        xA[k] = (vA && vc) ? pA[col] : 0.0f;
        xB[k] = (vB && vc) ? pB[col] : 0.0f;
    }

    float4 o;
    // ow0   (pw=0): cols {c-1,c}   -> idx 0,1 ; col-weights {3,1}
    o.x = xA[0]*w0r[3] + xA[1]*w0r[1] + xB[0]*w1r[3] + xB[1]*w1r[1] + bb;
    // ow0+1 (pw=1): cols {c,c+1}   -> idx 1,2 ; col-weights {2,0}
    o.y = xA[1]*w0r[2] + xA[2]*w0r[0] + xB[1]*w1r[2] + xB[2]*w1r[0] + bb;
    // ow0+2 (pw=0): cols {c,c+1}   -> idx 1,2 ; col-weights {3,1}
    o.z = xA[1]*w0r[3] + xA[2]*w0r[1] + xB[1]*w1r[3] + xB[2]*w1r[1] + bb;
    // ow0+3 (pw=1): cols {c+1,c+2} -> idx 2,3 ; col-weights {2,0}
    o.w = xA[2]*w0r[2] + xA[3]*w0r[0] + xB[2]*w1r[2] + xB[3]*w1r[0] + bb;

    float4* outp = (float4*)(out + ((size_t)(b * NS + s) * OHH + oh) * OWW + qw * 4);
    *outp = o;
}

extern "C" void kernel_launch(void* const* d_in, const int* in_sizes, int n_in,
                              void* d_out, int out_size, void* d_ws, size_t ws_size,
                              hipStream_t stream) {
    const float* x    = (const float*)d_in[0];
    const float* w    = (const float*)d_in[1];
    const float* bias = (const float*)d_in[2];
    float* out        = (float*)d_out;

    // 512 rows * 128 quads = 65536 threads per (b,s) image -> 256 blocks of 256
    dim3 grid(256, NS, 8);
    convt2x_kernel<<<grid, 256, 0, stream>>>(x, w, bias, out);
}

// Round 2
// 254.528 us; speedup vs baseline: 1.1507x; 1.1507x over previous
//
#include <hip/hip_runtime.h>

// ConvTranspose2d, stride=2, pad=1, k=4, groups=24 (one channel each).
// x: [8,1,24,256,256] f32; w: [24,1,1,4,4] f32; b: [24] f32
// y: [8,1,24,512,512] f32
//
// Output row 2r   (ph=0): input rows {r-1, r}   with weight rows {3, 1}
// Output row 2r+1 (ph=1): input rows {r,   r+1} with weight rows {2, 0}
// Output col 2q   (pw=0): input cols {q-1, q}   with weight cols {3, 1}
// Output col 2q+1 (pw=1): input cols {q,   q+1} with weight cols {2, 0}
//
// Thread tile: 2 output rows x 8 output cols = 16 outputs.
//   row pair r = lin>>6 (wave-uniform), col tile t = lin&63, c = 4t.
//   Needs input rows r-1,r,r+1, cols c-1..c+4 -> load cols c-2..c+5 as
//   float2 | float4 | float2 (all naturally aligned).

#define NS 24
#define IH 256
#define IW 256
#define OHH 512
#define OWW 512

__global__ __launch_bounds__(256) void convt2x_tile_kernel(
    const float* __restrict__ x, const float* __restrict__ w,
    const float* __restrict__ bias, float* __restrict__ out)
{
    const int b   = blockIdx.z;
    const int s   = blockIdx.y;
    const int lin = blockIdx.x * 256 + threadIdx.x;   // 0 .. 16383
    const int t   = lin & 63;    // column tile (lane id within wave)
    const int r   = lin >> 6;    // input row pair index, wave-uniform
    const int c   = t * 4;       // base input column

    const float* ximg = x + (size_t)(b * NS + s) * IH * IW;

    // Weights + bias: address uniform in the block -> scalar loads.
    const float* wv = w + s * 16;
    float W[16];
    #pragma unroll
    for (int k = 0; k < 16; ++k) W[k] = wv[k];
    const float bb = bias[s];

    // ---- load 3 input rows x 8 cols (cols c-2 .. c+5) ----
    float xr[3][8];
    #pragma unroll
    for (int i = 0; i < 3; ++i) {
        const int rr = r - 1 + i;
        const bool vr = (rr >= 0) && (rr < IH);
        const float* p = ximg + (size_t)rr * IW + c;
        float2 lo = (vr && t > 0)  ? *(const float2*)(p - 2) : make_float2(0.f, 0.f);
        float4 md = vr             ? *(const float4*)(p)     : make_float4(0.f, 0.f, 0.f, 0.f);
        float2 hi = (vr && t < 63) ? *(const float2*)(p + 4) : make_float2(0.f, 0.f);
        xr[i][0] = lo.x; xr[i][1] = lo.y;
        xr[i][2] = md.x; xr[i][3] = md.y; xr[i][4] = md.z; xr[i][5] = md.w;
        xr[i][6] = hi.x; xr[i][7] = hi.y;
    }

    // ---- compute 2 output rows x 8 cols ----
    // row 2r  : a = xr[0] (w row 3), b = xr[1] (w row 1)
    // row 2r+1: a = xr[1] (w row 2), b = xr[2] (w row 0)
    float o0[8], o1[8];
    #pragma unroll
    for (int j = 0; j < 8; ++j) {
        const int h = j >> 1;
        if ((j & 1) == 0) {
            const int i1 = h + 1, i2 = h + 2;   // cols base-1, base
            o0[j] = xr[0][i1] * W[12 + 3] + xr[0][i2] * W[12 + 1]
                  + xr[1][i1] * W[4 + 3]  + xr[1][i2] * W[4 + 1] + bb;
            o1[j] = xr[1][i1] * W[8 + 3]  + xr[1][i2] * W[8 + 1]
                  + xr[2][i1] * W[0 + 3]  + xr[2][i2] * W[0 + 1] + bb;
        } else {
            const int i2 = h + 2, i3 = h + 3;   // cols base, base+1
            o0[j] = xr[0][i2] * W[12 + 2] + xr[0][i3] * W[12 + 0]
                  + xr[1][i2] * W[4 + 2]  + xr[1][i3] * W[4 + 0] + bb;
            o1[j] = xr[1][i2] * W[8 + 2]  + xr[1][i3] * W[8 + 0]
                  + xr[2][i2] * W[0 + 2]  + xr[2][i3] * W[0 + 0] + bb;
        }
    }

    // ---- store: 2 rows x 2 float4 each ----
    float* orow0 = out + ((size_t)(b * NS + s) * OHH + 2 * r)     * OWW + t * 8;
    float* orow1 = out + ((size_t)(b * NS + s) * OHH + 2 * r + 1) * OWW + t * 8;
    ((float4*)orow0)[0] = make_float4(o0[0], o0[1], o0[2], o0[3]);
    ((float4*)orow0)[1] = make_float4(o0[4], o0[5], o0[6], o0[7]);
    ((float4*)orow1)[0] = make_float4(o1[0], o1[1], o1[2], o1[3]);
    ((float4*)orow1)[1] = make_float4(o1[4], o1[5], o1[6], o1[7]);
}

extern "C" void kernel_launch(void* const* d_in, const int* in_sizes, int n_in,
                              void* d_out, int out_size, void* d_ws, size_t ws_size,
                              hipStream_t stream) {
    const float* x    = (const float*)d_in[0];
    const float* w    = (const float*)d_in[1];
    const float* bias = (const float*)d_in[2];
    float* out        = (float*)d_out;

    // per (b,s) image: 256 row-pairs x 64 col-tiles = 16384 threads -> 64 blocks of 256
    dim3 grid(64, NS, 8);
    convt2x_tile_kernel<<<grid, 256, 0, stream>>>(x, w, bias, out);
}

// Round 3
// 247.111 us; speedup vs baseline: 1.1852x; 1.0300x over previous
//
#include <hip/hip_runtime.h>

// ConvTranspose2d, stride=2, pad=1, k=4, groups=24 (one channel each).
// x: [8,1,24,256,256] f32; w: [24,1,1,4,4] f32; b: [24] f32
// y: [8,1,24,512,512] f32
//
// Output row 2r   (ph=0): input rows {r-1, r}   weight rows {3, 1}
// Output row 2r+1 (ph=1): input rows {r,   r+1} weight rows {2, 0}
// Output col 2q   (pw=0): input cols {q-1, q}   weight cols {3, 1}
// Output col 2q+1 (pw=1): input cols {q,   q+1} weight cols {2, 0}
//
// Thread tile: 2 output rows x 8 output cols. Lane t (of 64) loads ONE
// aligned float4 per input row (cols 4t..4t+3) — a wave covers the whole
// 256-col row exactly once. Halo cols c-1 / c+4 come from neighbor lanes
// via __shfl (ds_bpermute, no LDS, no extra VMEM).

#define NS 24
#define IH 256
#define IW 256
#define OHH 512
#define OWW 512

__global__ __launch_bounds__(256) void convt2x_shfl_kernel(
    const float* __restrict__ x, const float* __restrict__ w,
    const float* __restrict__ bias, float* __restrict__ out)
{
    const int b   = blockIdx.z;
    const int s   = blockIdx.y;
    const int lin = blockIdx.x * 256 + threadIdx.x;   // 0 .. 16383
    const int t   = lin & 63;    // lane id = column tile
    const int r   = lin >> 6;    // input row-pair index, wave-uniform

    const float* ximg = x + (size_t)(b * NS + s) * IH * IW;

    // Weights + bias: block-uniform address -> scalar loads.
    const float* wv = w + s * 16;
    float W[16];
    #pragma unroll
    for (int k = 0; k < 16; ++k) W[k] = wv[k];
    const float bb = bias[s];

    // ---- 3 input rows, 6 needed cols each: c-1 .. c+4 (c = 4t) ----
    float X[3][6];
    #pragma unroll
    for (int i = 0; i < 3; ++i) {
        const int rr = r - 1 + i;                 // wave-uniform
        float4 m = make_float4(0.f, 0.f, 0.f, 0.f);
        if (rr >= 0 && rr < IH)                   // scalar branch (uniform)
            m = *(const float4*)(ximg + (size_t)rr * IW + 4 * t);
        const float lft = __shfl(m.w, t - 1);     // lane t-1's col 4t-1
        const float rgt = __shfl(m.x, t + 1);     // lane t+1's col 4t+4
        X[i][0] = (t == 0)  ? 0.f : lft;
        X[i][1] = m.x; X[i][2] = m.y; X[i][3] = m.z; X[i][4] = m.w;
        X[i][5] = (t == 63) ? 0.f : rgt;
    }

    // ---- compute 2 output rows x 8 cols ----
    float o0[8], o1[8];
    #pragma unroll
    for (int h = 0; h < 4; ++h) {
        o0[2*h]   = X[0][h]  *W[15] + X[0][h+1]*W[13]
                  + X[1][h]  *W[7]  + X[1][h+1]*W[5]  + bb;
        o0[2*h+1] = X[0][h+1]*W[14] + X[0][h+2]*W[12]
                  + X[1][h+1]*W[6]  + X[1][h+2]*W[4]  + bb;
        o1[2*h]   = X[1][h]  *W[11] + X[1][h+1]*W[9]
                  + X[2][h]  *W[3]  + X[2][h+1]*W[1]  + bb;
        o1[2*h+1] = X[1][h+1]*W[10] + X[1][h+2]*W[8]
                  + X[2][h+1]*W[2]  + X[2][h+2]*W[0]  + bb;
    }

    // ---- store: 2 rows x 2 float4 each (1 KB contiguous per wave-inst) ----
    float* orow0 = out + ((size_t)(b * NS + s) * OHH + 2 * r)     * OWW + t * 8;
    float* orow1 = orow0 + OWW;
    ((float4*)orow0)[0] = make_float4(o0[0], o0[1], o0[2], o0[3]);
    ((float4*)orow0)[1] = make_float4(o0[4], o0[5], o0[6], o0[7]);
    ((float4*)orow1)[0] = make_float4(o1[0], o1[1], o1[2], o1[3]);
    ((float4*)orow1)[1] = make_float4(o1[4], o1[5], o1[6], o1[7]);
}

extern "C" void kernel_launch(void* const* d_in, const int* in_sizes, int n_in,
                              void* d_out, int out_size, void* d_ws, size_t ws_size,
                              hipStream_t stream) {
    const float* x    = (const float*)d_in[0];
    const float* w    = (const float*)d_in[1];
    const float* bias = (const float*)d_in[2];
    float* out        = (float*)d_out;

    // per (b,s) image: 256 row-pairs x 64 lanes = 16384 threads -> 64 blocks of 256
    dim3 grid(64, NS, 8);
    convt2x_shfl_kernel<<<grid, 256, 0, stream>>>(x, w, bias, out);
}